// Round 6
// baseline (1283.421 us; speedup 1.0000x reference)
//
#include <hip/hip_runtime.h>
#include <hip/hip_bf16.h>

using bf16 = __hip_bfloat16;
typedef __attribute__((ext_vector_type(8))) short short8;
typedef __attribute__((ext_vector_type(4))) short s16x4;
typedef __attribute__((ext_vector_type(4))) float f32x4;

#define MFMA(a,b,c) __builtin_amdgcn_mfma_f32_16x16x32_bf16(a, b, c, 0, 0, 0)

#define B_      128
#define C_      1024
#define NH      8
#define HD      128
#define HW      24
#define NTOK    576
#define QH      12
#define QN      144

static __device__ __forceinline__ float bf2f(bf16 v) { return __bfloat162float(v); }
static __device__ __forceinline__ bf16  f2bf(float v) { return __float2bfloat16(v); }
static __device__ __forceinline__ float s2f(short s) {
    return __uint_as_float(((unsigned)(unsigned short)s) << 16);
}
static __device__ __forceinline__ unsigned bfbits(float v) {
    bf16 t = f2bf(v);
    return (unsigned)*(unsigned short*)&t;
}

__device__ __forceinline__ void gll16(const bf16* src, bf16* dst_lds) {
    __builtin_amdgcn_global_load_lds(
        (__attribute__((address_space(1))) const unsigned int*)src,
        (__attribute__((address_space(3))) unsigned int*)dst_lds,
        16, 0, 0);
}

// ---------------- transpose + fp32->bf16 convert: out[c][r] = in[r][c] ----------------
__global__ __launch_bounds__(256) void transpose_cvt(
    const float* __restrict__ in, bf16* __restrict__ out,
    int R, int Ccols, size_t ibs, size_t obs)
{
    __shared__ float tile[32][33];
    const float* ib = in + (size_t)blockIdx.z * ibs;
    bf16* ob = out + (size_t)blockIdx.z * obs;
    int c0 = blockIdx.x * 32, r0 = blockIdx.y * 32;
    int tx = threadIdx.x & 31, ty = threadIdx.x >> 5;
    #pragma unroll
    for (int i = 0; i < 32; i += 8)
        tile[ty + i][tx] = ib[(size_t)(r0 + ty + i) * Ccols + c0 + tx];
    __syncthreads();
    #pragma unroll
    for (int i = 0; i < 32; i += 8)
        ob[(size_t)(c0 + ty + i) * R + r0 + tx] = f2bf(tile[tx][ty + i]);
}

// ---------------- 4 weight transposes in one launch (z selects weight) ----------------
__global__ __launch_bounds__(256) void transpose_w4(
    const float* __restrict__ p0, const float* __restrict__ p1,
    const float* __restrict__ p2, const float* __restrict__ p3,
    bf16* __restrict__ out)
{
    __shared__ float tile[32][33];
    int z = blockIdx.z;
    const float* ib = (z == 0) ? p0 : (z == 1) ? p1 : (z == 2) ? p2 : p3;
    bf16* ob = out + (size_t)z * 1048576;
    int c0 = blockIdx.x * 32, r0 = blockIdx.y * 32;
    int tx = threadIdx.x & 31, ty = threadIdx.x >> 5;
    #pragma unroll
    for (int i = 0; i < 32; i += 8)
        tile[ty + i][tx] = ib[(size_t)(r0 + ty + i) * 1024 + c0 + tx];
    __syncthreads();
    #pragma unroll
    for (int i = 0; i < 32; i += 8)
        ob[(size_t)(c0 + ty + i) * 1024 + r0 + tx] = f2bf(tile[tx][ty + i]);
}

// ---------------- 3x3 s2 avg pool (count_include_pad), xt[B*N][C] -> xp[B*qN][C] ------
__global__ __launch_bounds__(256) void pool_kernel(const bf16* __restrict__ xt,
                                                   bf16* __restrict__ xp)
{
    int bqn = blockIdx.x;
    int b = bqn / QN, qn = bqn % QN;
    int y = qn / QH, x = qn % QH;
    int t = threadIdx.x;
    float s0 = 0, s1 = 0, s2 = 0, s3 = 0;
    for (int dy = 0; dy < 3; dy++) {
        int hy = 2 * y - 1 + dy;
        if (hy < 0 || hy >= HW) continue;
        for (int dx = 0; dx < 3; dx++) {
            int hx = 2 * x - 1 + dx;
            if (hx < 0 || hx >= HW) continue;
            const bf16* row = xt + (size_t)(b * NTOK + hy * HW + hx) * C_;
            s0 += bf2f(row[t]);
            s1 += bf2f(row[t + 256]);
            s2 += bf2f(row[t + 512]);
            s3 += bf2f(row[t + 768]);
        }
    }
    bf16* o = xp + (size_t)bqn * C_;
    const float n = 1.f / 9.f;
    o[t] = f2bf(s0 * n); o[t + 256] = f2bf(s1 * n);
    o[t + 512] = f2bf(s2 * n); o[t + 768] = f2bf(s3 * n);
}

// ---------------- NT GEMM: C[m][n] = sum_k A[m][k]*Bt[n][k], K=1024 -------------------
// EPI 0: bf16 row-major [M][1024]
// EPI 2: fp32 out + bias: row=channel, col=token -> out[b*147456 + ch*144 + qn]
// EPI 3: K frag-ready (32-key tiles): row=token(b*576+n), col=channel
// EPI 4: V frag-ready (32-key tiles): row=channel, col=token(b*576+n)
template<int EPI>
__global__ __launch_bounds__(256, 2) void gemm_nt(
    const bf16* __restrict__ A, const bf16* __restrict__ Bt,
    void* __restrict__ Cout, const float* __restrict__ bias)
{
    __shared__ bf16 lds[2][2][128 * 64];
    const int tid = threadIdx.x;
    const int wv = tid >> 6, ln = tid & 63;
    const int m0 = blockIdx.x * 128, n0 = blockIdx.y * 128;
    const int wr = wv >> 1, wc = wv & 1;
    const int l15 = ln & 15, l4 = ln >> 4;
    const int r8 = ln >> 3, sl = ln & 7;
    const int sg = sl ^ r8;

    const bf16* gA = A + (size_t)m0 * C_;
    const bf16* gB = Bt + (size_t)n0 * C_;

    f32x4 zero = {0.f, 0.f, 0.f, 0.f};
    f32x4 acc[4][4];
    #pragma unroll
    for (int i = 0; i < 4; i++)
        #pragma unroll
        for (int j = 0; j < 4; j++) acc[i][j] = zero;

    auto stage = [&](int kt, int d) {
        const bf16* sa = gA + kt * 64;
        const bf16* sb = gB + kt * 64;
        bf16* la = lds[d][0];
        bf16* lb = lds[d][1];
        #pragma unroll
        for (int i = 0; i < 4; i++) {
            int chunk = wv * 4 + i;
            gll16(sa + (size_t)(chunk * 8 + r8) * C_ + sg * 8, la + chunk * 512);
            gll16(sb + (size_t)(chunk * 8 + r8) * C_ + sg * 8, lb + chunk * 512);
        }
    };

    stage(0, 0);
    asm volatile("s_waitcnt vmcnt(0)");
    __syncthreads();

    int cur = 0;
    for (int kt = 0; kt < 16; kt++) {
        if (kt < 15) stage(kt + 1, cur ^ 1);
        const bf16* la = lds[cur][0];
        const bf16* lb = lds[cur][1];
        #pragma unroll
        for (int ks = 0; ks < 2; ks++) {
            short8 af[4], bfr[4];
            #pragma unroll
            for (int fm = 0; fm < 4; fm++) {
                int row = wr * 64 + fm * 16 + l15;
                int slot = (ks * 4 + l4) ^ (row & 7);
                af[fm] = *(const short8*)((const char*)la + row * 128 + slot * 16);
            }
            #pragma unroll
            for (int fn = 0; fn < 4; fn++) {
                int row = wc * 64 + fn * 16 + l15;
                int slot = (ks * 4 + l4) ^ (row & 7);
                bfr[fn] = *(const short8*)((const char*)lb + row * 128 + slot * 16);
            }
            #pragma unroll
            for (int fm = 0; fm < 4; fm++)
                #pragma unroll
                for (int fn = 0; fn < 4; fn++)
                    acc[fm][fn] = MFMA(af[fm], bfr[fn], acc[fm][fn]);
        }
        asm volatile("s_waitcnt vmcnt(0)");
        __syncthreads();
        cur ^= 1;
    }

    #pragma unroll
    for (int fm = 0; fm < 4; fm++) {
        #pragma unroll
        for (int fn = 0; fn < 4; fn++) {
            #pragma unroll
            for (int r = 0; r < 4; r++) {
                int row = m0 + wr * 64 + fm * 16 + l4 * 4 + r;
                int col = n0 + wc * 64 + fn * 16 + l15;
                float v = acc[fm][fn][r];
                if constexpr (EPI == 0) {
                    ((bf16*)Cout)[(size_t)row * C_ + col] = f2bf(v);
                } else if constexpr (EPI == 2) {
                    int bb = col / QN, qn = col % QN;
                    ((float*)Cout)[(size_t)bb * (C_ * QN) + (size_t)row * QN + qn] =
                        v + bias[row];
                } else if constexpr (EPI == 3) {
                    // K frag-ready: row = global token, col = channel
                    int b = row / NTOK, n = row % NTOK;
                    int h = col >> 7, ci = col & 127;
                    int kt2 = n >> 5, kf = (n >> 4) & 1, klane = n & 15;
                    int ks2 = ci >> 5, chunk = (ci >> 3) & 3, e = ci & 7;
                    int lane = chunk * 16 + klane;
                    size_t addr = ((((size_t)(b * NH + h) * 18 + kt2) * 2 + kf) * 4 + ks2) * 512
                                  + lane * 8 + e;
                    ((bf16*)Cout)[addr] = f2bf(v);
                } else {
                    // V frag-ready: row = channel, col = global token
                    int b = col / NTOK, n = col % NTOK;
                    int h = row >> 7, ci = row & 127;
                    int hf = (ci >> 4) & 7, lanelo = ci & 15;
                    int kt2 = n >> 5, chunk = (n >> 3) & 3, e = n & 7;
                    int lane = chunk * 16 + lanelo;
                    size_t addr = (((size_t)(b * NH + h) * 18 + kt2) * 8 + hf) * 512
                                  + lane * 8 + e;
                    ((bf16*)Cout)[addr] = f2bf(v);
                }
            }
        }
    }
}

// ---------------- fused pooled-Q attention, barrier-free -------------------------------
// grid: B*NH*3 blocks of 192 thr (3 waves); each wave owns 16 q-rows, fully independent.
// K/V fragments loaded DIRECTLY global->VGPR (coalesced 1KB/instr) from frag-ready
// layouts; per-wave rel tables + per-wave P bounce; no __syncthreads anywhere.
// XCD swizzle: consecutive work items (3 q-blocks of same head) -> same XCD L2.
__global__ __launch_bounds__(192, 4) void attn_kernel(
    const bf16* __restrict__ qbuf, const bf16* __restrict__ kfr,
    const bf16* __restrict__ vfr, const float* __restrict__ rph,
    const float* __restrict__ rpw, bf16* __restrict__ attno)
{
    __shared__ float relh[3][16 * 24];    // 4.5 KB
    __shared__ float relw[3][16 * 24];    // 4.5 KB
    __shared__ char  plds[3][1024];       // 3 KB

    const int work = ((blockIdx.x & 7) * 384) + (blockIdx.x >> 3);   // m157 swizzle
    const int b = work / 24;
    const int rem = work - b * 24;
    const int h = rem / 3, qblk = rem - (rem / 3) * 3;
    const int w = threadIdx.x >> 6, ln = threadIdx.x & 63;
    const int l15 = ln & 15, l4 = ln >> 4;
    const int qr0 = qblk * 48 + w * 16;   // wave's first q-row

    const bf16* qbase = qbuf + ((size_t)(b * QN + qr0) * C_ + h * HD);
    const bf16* kh = kfr + (size_t)(b * NH + h) * 18 * 4096;
    const bf16* vh = vfr + (size_t)(b * NH + h) * 18 * 4096;

    // ---- per-wave relative-position bias tables (wave's own 16 rows) ----
    {
        int qr = ln >> 2, kkg = ln & 3;
        int row = qr0 + qr;
        int y = row / 12, x = row - (row / 12) * 12;
        const short8* qrow = (const short8*)(qbuf + ((size_t)(b * QN + row) * C_ + h * HD));
        float sh[6] = {0, 0, 0, 0, 0, 0}, sw[6] = {0, 0, 0, 0, 0, 0};
        for (int c0 = 0; c0 < 16; c0++) {
            short8 qv = qrow[c0];
            float qf[8];
            #pragma unroll
            for (int j = 0; j < 8; j++) qf[j] = s2f(qv[j]);
            #pragma unroll
            for (int j = 0; j < 6; j++) {
                int kk = j * 4 + kkg;
                const f32x4* rh = (const f32x4*)(rph + (size_t)(2 * y - kk + 23) * HD + c0 * 8);
                const f32x4* rw = (const f32x4*)(rpw + (size_t)(2 * x - kk + 23) * HD + c0 * 8);
                f32x4 h0 = rh[0], h1 = rh[1], w0 = rw[0], w1 = rw[1];
                #pragma unroll
                for (int u = 0; u < 4; u++) {
                    sh[j] = fmaf(qf[u], h0[u], sh[j]);
                    sw[j] = fmaf(qf[u], w0[u], sw[j]);
                    sh[j] = fmaf(qf[u + 4], h1[u], sh[j]);
                    sw[j] = fmaf(qf[u + 4], w1[u], sw[j]);
                }
            }
        }
        #pragma unroll
        for (int j = 0; j < 6; j++) {
            relh[w][qr * 24 + j * 4 + kkg] = sh[j];
            relw[w][qr * 24 + j * 4 + kkg] = sw[j];
        }
    }
    asm volatile("s_waitcnt lgkmcnt(0)" ::: "memory");   // per-wave LDS visibility

    // ---- persistent q fragments (B-operand: row=q=l15, k=ks*32+l4*8+e) ----
    short8 qfr[4];
    #pragma unroll
    for (int ks = 0; ks < 4; ks++)
        qfr[ks] = *(const short8*)(qbase + (size_t)l15 * C_ + ks * 32 + l4 * 8);

    f32x4 zero = {0.f, 0.f, 0.f, 0.f};
    f32x4 Of[8];
    #pragma unroll
    for (int hf = 0; hf < 8; hf++) Of[hf] = zero;
    float mrun = -1e30f, lrun = 0.f;

    const float scale = 0.08838834764831845f;  // 1/sqrt(128)
    const int rbase = l15 * 24;                // this lane's q row in the wave table

    for (int kt = 0; kt < 18; kt++) {
        // K fragments direct from global (coalesced: lane ln reads bytes ln*16)
        short8 kb[8];
        #pragma unroll
        for (int i = 0; i < 8; i++)
            kb[i] = *(const short8*)(kh + ((size_t)kt * 8 + i) * 512 + ln * 8);
        // S = K @ q^T (swapped): lane holds S[key=kf*16+l4*4+r][q=l15]
        f32x4 S[2];
        #pragma unroll
        for (int kf = 0; kf < 2; kf++) {
            f32x4 acc = zero;
            #pragma unroll
            for (int ks = 0; ks < 4; ks++) acc = MFMA(kb[kf * 4 + ks], qfr[ks], acc);
            S[kf] = acc;
        }
        // V fragments: issue early so latency hides under softmax
        short8 vb[8];
        #pragma unroll
        for (int i = 0; i < 8; i++)
            vb[i] = *(const short8*)(vh + ((size_t)kt * 8 + i) * 512 + ln * 8);
        // scale + rel-pos bias (per-lane keys)
        #pragma unroll
        for (int kf = 0; kf < 2; kf++) {
            #pragma unroll
            for (int r = 0; r < 4; r++) {
                int key = kt * 32 + kf * 16 + l4 * 4 + r;
                int kr = key / 24, kc = key - kr * 24;
                S[kf][r] = S[kf][r] * scale + relh[w][rbase + kr] + relw[w][rbase + kc];
            }
        }
        // in-lane softmax (row = this lane's q; 8 keys/lane, x4 lanes)
        float pm = fmaxf(fmaxf(fmaxf(S[0][0], S[0][1]), fmaxf(S[0][2], S[0][3])),
                         fmaxf(fmaxf(S[1][0], S[1][1]), fmaxf(S[1][2], S[1][3])));
        pm = fmaxf(pm, __shfl_xor(pm, 16, 64));
        pm = fmaxf(pm, __shfl_xor(pm, 32, 64));
        if (!__all(pm <= mrun + 8.f)) {       // defer-max (T13)
            float mn = fmaxf(mrun, pm);
            float alpha = __expf(mrun - mn);
            #pragma unroll
            for (int hf = 0; hf < 8; hf++)
                #pragma unroll
                for (int r = 0; r < 4; r++) Of[hf][r] *= alpha;
            lrun *= alpha;
            mrun = mn;
        }
        float ps = 0.f;
        #pragma unroll
        for (int kf = 0; kf < 2; kf++)
            #pragma unroll
            for (int r = 0; r < 4; r++) {
                float p = __expf(S[kf][r] - mrun);
                S[kf][r] = p;
                ps += p;
            }
        ps += __shfl_xor(ps, 16, 64);
        ps += __shfl_xor(ps, 32, 64);
        lrun += ps;
        // pack P -> per-wave LDS bounce (row=q=l15, 32 keys x bf16 = 64B/row)
        #pragma unroll
        for (int kf = 0; kf < 2; kf++) {
            unsigned u0 = bfbits(S[kf][0]) | (bfbits(S[kf][1]) << 16);
            unsigned u1 = bfbits(S[kf][2]) | (bfbits(S[kf][3]) << 16);
            *(unsigned long long*)(&plds[w][l15 * 64 + kf * 32 + l4 * 8]) =
                ((unsigned long long)u1 << 32) | u0;
        }
        // P B-frag: row=q=l15, key=l4*8+e
        short8 pf = *(const short8*)(&plds[w][l15 * 64 + l4 * 16]);
        // PV swapped: Of[hd][q]
        #pragma unroll
        for (int hf = 0; hf < 8; hf++)
            Of[hf] = MFMA(vb[hf], pf, Of[hf]);
    }

    // epilogue: O/l + q residual; lane stores row q=l15, hd = hf*16 + l4*4 + r
    bf16* obase = attno + ((size_t)(b * QN + qr0) * C_ + h * HD);
    float inv = 1.f / lrun;
    #pragma unroll
    for (int hf = 0; hf < 8; hf++) {
        s16x4 qres = *(const s16x4*)(qbase + (size_t)l15 * C_ + hf * 16 + l4 * 4);
        s16x4 o;
        #pragma unroll
        for (int r = 0; r < 4; r++) {
            float v = Of[hf][r] * inv + s2f(qres[r]);
            o[r] = (short)bfbits(v);
        }
        *(s16x4*)(obase + (size_t)l15 * C_ + hf * 16 + l4 * 4) = o;
    }
}

extern "C" void kernel_launch(void* const* d_in, const int* in_sizes, int n_in,
                              void* d_out, int out_size, void* d_ws, size_t ws_size,
                              hipStream_t stream)
{
    const float* x   = (const float*)d_in[0];
    const float* Wq  = (const float*)d_in[1];
    const float* Wk  = (const float*)d_in[2];
    const float* Wv  = (const float*)d_in[3];
    const float* Wp  = (const float*)d_in[4];
    const float* bp  = (const float*)d_in[5];
    const float* rph = (const float*)d_in[6];
    const float* rpw = (const float*)d_in[7];

    char* ws = (char*)d_ws;
    const size_t MB = 1024 * 1024;
    bf16* Wqt  = (bf16*)(ws + 0 * MB);
    bf16* Wkt  = (bf16*)(ws + 2 * MB);
    bf16* Wvt  = (bf16*)(ws + 4 * MB);
    bf16* Wpt  = (bf16*)(ws + 6 * MB);
    bf16* xt   = (bf16*)(ws + 8 * MB);          // 144 MB, reused as attno
    bf16* kfrb = (bf16*)(ws + 152 * MB);        // 144 MB (frag-ready K)
    bf16* vfrb = (bf16*)(ws + 296 * MB);        // 144 MB (frag-ready V)
    bf16* xp   = (bf16*)(ws + 440 * MB);        // 36 MB
    bf16* qbuf = (bf16*)(ws + 476 * MB);        // 36 MB -> end 512 MB
    bf16* attno = xt;

    transpose_w4<<<dim3(32, 32, 4), 256, 0, stream>>>(Wq, Wk, Wv, Wp, (bf16*)ws);
    transpose_cvt<<<dim3(18, 32, 128), 256, 0, stream>>>(
        x, xt, 1024, 576, (size_t)1024 * 576, (size_t)576 * 1024);
    pool_kernel<<<dim3(B_ * QN), 256, 0, stream>>>(xt, xp);
    gemm_nt<3><<<dim3(576, 8), 256, 0, stream>>>(xt, Wkt, kfrb, nullptr);
    gemm_nt<4><<<dim3(8, 576), 256, 0, stream>>>(Wvt, xt, vfrb, nullptr);
    gemm_nt<0><<<dim3(144, 8), 256, 0, stream>>>(xp, Wqt, qbuf, nullptr);
    attn_kernel<<<dim3(B_ * NH * 3), 192, 0, stream>>>(qbuf, kfrb, vfrb, rph, rpw, attno);
    gemm_nt<2><<<dim3(8, 144), 256, 0, stream>>>(Wpt, attno, d_out, bp);
}

// Round 7
// 1281.192 us; speedup vs baseline: 1.0017x; 1.0017x over previous
//
#include <hip/hip_runtime.h>
#include <hip/hip_bf16.h>

using bf16 = __hip_bfloat16;
typedef __attribute__((ext_vector_type(8))) short short8;
typedef __attribute__((ext_vector_type(4))) short s16x4;
typedef __attribute__((ext_vector_type(4))) float f32x4;

#define MFMA(a,b,c) __builtin_amdgcn_mfma_f32_16x16x32_bf16(a, b, c, 0, 0, 0)

#define B_      128
#define C_      1024
#define NH      8
#define HD      128
#define HW      24
#define NTOK    576
#define QH      12
#define QN      144

static __device__ __forceinline__ float bf2f(bf16 v) { return __bfloat162float(v); }
static __device__ __forceinline__ bf16  f2bf(float v) { return __float2bfloat16(v); }
static __device__ __forceinline__ float s2f(short s) {
    return __uint_as_float(((unsigned)(unsigned short)s) << 16);
}
static __device__ __forceinline__ unsigned bfbits(float v) {
    bf16 t = f2bf(v);
    return (unsigned)*(unsigned short*)&t;
}

__device__ __forceinline__ void gll16(const bf16* src, bf16* dst_lds) {
    __builtin_amdgcn_global_load_lds(
        (__attribute__((address_space(1))) const unsigned int*)src,
        (__attribute__((address_space(3))) unsigned int*)dst_lds,
        16, 0, 0);
}

// ---------------- transpose + fp32->bf16 convert: out[c][r] = in[r][c] ----------------
__global__ __launch_bounds__(256) void transpose_cvt(
    const float* __restrict__ in, bf16* __restrict__ out,
    int R, int Ccols, size_t ibs, size_t obs)
{
    __shared__ float tile[32][33];
    const float* ib = in + (size_t)blockIdx.z * ibs;
    bf16* ob = out + (size_t)blockIdx.z * obs;
    int c0 = blockIdx.x * 32, r0 = blockIdx.y * 32;
    int tx = threadIdx.x & 31, ty = threadIdx.x >> 5;
    #pragma unroll
    for (int i = 0; i < 32; i += 8)
        tile[ty + i][tx] = ib[(size_t)(r0 + ty + i) * Ccols + c0 + tx];
    __syncthreads();
    #pragma unroll
    for (int i = 0; i < 32; i += 8)
        ob[(size_t)(c0 + ty + i) * R + r0 + tx] = f2bf(tile[tx][ty + i]);
}

// ---------------- 4 weight transposes in one launch (z selects weight) ----------------
__global__ __launch_bounds__(256) void transpose_w4(
    const float* __restrict__ p0, const float* __restrict__ p1,
    const float* __restrict__ p2, const float* __restrict__ p3,
    bf16* __restrict__ out)
{
    __shared__ float tile[32][33];
    int z = blockIdx.z;
    const float* ib = (z == 0) ? p0 : (z == 1) ? p1 : (z == 2) ? p2 : p3;
    bf16* ob = out + (size_t)z * 1048576;
    int c0 = blockIdx.x * 32, r0 = blockIdx.y * 32;
    int tx = threadIdx.x & 31, ty = threadIdx.x >> 5;
    #pragma unroll
    for (int i = 0; i < 32; i += 8)
        tile[ty + i][tx] = ib[(size_t)(r0 + ty + i) * 1024 + c0 + tx];
    __syncthreads();
    #pragma unroll
    for (int i = 0; i < 32; i += 8)
        ob[(size_t)(c0 + ty + i) * 1024 + r0 + tx] = f2bf(tile[tx][ty + i]);
}

// ---------------- 3x3 s2 avg pool (count_include_pad), xt[B*N][C] -> xp[B*qN][C] ------
__global__ __launch_bounds__(256) void pool_kernel(const bf16* __restrict__ xt,
                                                   bf16* __restrict__ xp)
{
    int bqn = blockIdx.x;
    int b = bqn / QN, qn = bqn % QN;
    int y = qn / QH, x = qn % QH;
    int t = threadIdx.x;
    float s0 = 0, s1 = 0, s2 = 0, s3 = 0;
    for (int dy = 0; dy < 3; dy++) {
        int hy = 2 * y - 1 + dy;
        if (hy < 0 || hy >= HW) continue;
        for (int dx = 0; dx < 3; dx++) {
            int hx = 2 * x - 1 + dx;
            if (hx < 0 || hx >= HW) continue;
            const bf16* row = xt + (size_t)(b * NTOK + hy * HW + hx) * C_;
            s0 += bf2f(row[t]);
            s1 += bf2f(row[t + 256]);
            s2 += bf2f(row[t + 512]);
            s3 += bf2f(row[t + 768]);
        }
    }
    bf16* o = xp + (size_t)bqn * C_;
    const float n = 1.f / 9.f;
    o[t] = f2bf(s0 * n); o[t + 256] = f2bf(s1 * n);
    o[t + 512] = f2bf(s2 * n); o[t + 768] = f2bf(s3 * n);
}

// ---------------- NT GEMM: C[m][n] = sum_k A[m][k]*Bt[n][k], K=1024 -------------------
// EPI 0: bf16 row-major [M][1024]
// EPI 2: fp32 out + bias: row=channel, col=token -> out[b*147456 + ch*144 + qn]
// EPI 3: K frag-ready (32-key tiles): row=token(b*576+n), col=channel
// EPI 4: V frag-ready (32-key tiles): row=channel, col=token(b*576+n)
template<int EPI>
__global__ __launch_bounds__(256, 2) void gemm_nt(
    const bf16* __restrict__ A, const bf16* __restrict__ Bt,
    void* __restrict__ Cout, const float* __restrict__ bias)
{
    __shared__ bf16 lds[2][2][128 * 64];
    const int tid = threadIdx.x;
    const int wv = tid >> 6, ln = tid & 63;
    const int m0 = blockIdx.x * 128, n0 = blockIdx.y * 128;
    const int wr = wv >> 1, wc = wv & 1;
    const int l15 = ln & 15, l4 = ln >> 4;
    const int r8 = ln >> 3, sl = ln & 7;
    const int sg = sl ^ r8;

    const bf16* gA = A + (size_t)m0 * C_;
    const bf16* gB = Bt + (size_t)n0 * C_;

    f32x4 zero = {0.f, 0.f, 0.f, 0.f};
    f32x4 acc[4][4];
    #pragma unroll
    for (int i = 0; i < 4; i++)
        #pragma unroll
        for (int j = 0; j < 4; j++) acc[i][j] = zero;

    auto stage = [&](int kt, int d) {
        const bf16* sa = gA + kt * 64;
        const bf16* sb = gB + kt * 64;
        bf16* la = lds[d][0];
        bf16* lb = lds[d][1];
        #pragma unroll
        for (int i = 0; i < 4; i++) {
            int chunk = wv * 4 + i;
            gll16(sa + (size_t)(chunk * 8 + r8) * C_ + sg * 8, la + chunk * 512);
            gll16(sb + (size_t)(chunk * 8 + r8) * C_ + sg * 8, lb + chunk * 512);
        }
    };

    stage(0, 0);
    asm volatile("s_waitcnt vmcnt(0)");
    __syncthreads();

    int cur = 0;
    for (int kt = 0; kt < 16; kt++) {
        if (kt < 15) stage(kt + 1, cur ^ 1);
        const bf16* la = lds[cur][0];
        const bf16* lb = lds[cur][1];
        #pragma unroll
        for (int ks = 0; ks < 2; ks++) {
            short8 af[4], bfr[4];
            #pragma unroll
            for (int fm = 0; fm < 4; fm++) {
                int row = wr * 64 + fm * 16 + l15;
                int slot = (ks * 4 + l4) ^ (row & 7);
                af[fm] = *(const short8*)((const char*)la + row * 128 + slot * 16);
            }
            #pragma unroll
            for (int fn = 0; fn < 4; fn++) {
                int row = wc * 64 + fn * 16 + l15;
                int slot = (ks * 4 + l4) ^ (row & 7);
                bfr[fn] = *(const short8*)((const char*)lb + row * 128 + slot * 16);
            }
            #pragma unroll
            for (int fm = 0; fm < 4; fm++)
                #pragma unroll
                for (int fn = 0; fn < 4; fn++)
                    acc[fm][fn] = MFMA(af[fm], bfr[fn], acc[fm][fn]);
        }
        asm volatile("s_waitcnt vmcnt(0)");
        __syncthreads();
        cur ^= 1;
    }

    #pragma unroll
    for (int fm = 0; fm < 4; fm++) {
        #pragma unroll
        for (int fn = 0; fn < 4; fn++) {
            #pragma unroll
            for (int r = 0; r < 4; r++) {
                int row = m0 + wr * 64 + fm * 16 + l4 * 4 + r;
                int col = n0 + wc * 64 + fn * 16 + l15;
                float v = acc[fm][fn][r];
                if constexpr (EPI == 0) {
                    ((bf16*)Cout)[(size_t)row * C_ + col] = f2bf(v);
                } else if constexpr (EPI == 2) {
                    int bb = col / QN, qn = col % QN;
                    ((float*)Cout)[(size_t)bb * (C_ * QN) + (size_t)row * QN + qn] =
                        v + bias[row];
                } else if constexpr (EPI == 3) {
                    // K frag-ready: row = global token, col = channel
                    int b = row / NTOK, n = row % NTOK;
                    int h = col >> 7, ci = col & 127;
                    int kt2 = n >> 5, kf = (n >> 4) & 1, klane = n & 15;
                    int ks2 = ci >> 5, chunk = (ci >> 3) & 3, e = ci & 7;
                    int lane = chunk * 16 + klane;
                    size_t addr = ((((size_t)(b * NH + h) * 18 + kt2) * 2 + kf) * 4 + ks2) * 512
                                  + lane * 8 + e;
                    ((bf16*)Cout)[addr] = f2bf(v);
                } else {
                    // V frag-ready: row = channel, col = global token
                    int b = col / NTOK, n = col % NTOK;
                    int h = row >> 7, ci = row & 127;
                    int hf = (ci >> 4) & 7, lanelo = ci & 15;
                    int kt2 = n >> 5, chunk = (n >> 3) & 3, e = n & 7;
                    int lane = chunk * 16 + lanelo;
                    size_t addr = (((size_t)(b * NH + h) * 18 + kt2) * 8 + hf) * 512
                                  + lane * 8 + e;
                    ((bf16*)Cout)[addr] = f2bf(v);
                }
            }
        }
    }
}

// ---------------- fused pooled-Q attention, barrier-free, spill-free -------------------
// grid: B*NH*3 blocks of 192 thr (3 waves); each wave owns 16 q-rows, independent.
// K loaded in two 4-frag batches (dead after QK); V loaded after (reuses regs);
// sched_barrier pins the order so peak live set stays < 128 VGPR (no scratch).
__global__ __launch_bounds__(192, 4) void attn_kernel(
    const bf16* __restrict__ qbuf, const bf16* __restrict__ kfr,
    const bf16* __restrict__ vfr, const float* __restrict__ rph,
    const float* __restrict__ rpw, bf16* __restrict__ attno)
{
    __shared__ float relh[3][16 * 24];    // 4.5 KB
    __shared__ float relw[3][16 * 24];    // 4.5 KB
    __shared__ char  plds[3][1024];       // 3 KB

    const int work = ((blockIdx.x & 7) * 384) + (blockIdx.x >> 3);   // m157 swizzle
    const int b = work / 24;
    const int rem = work - b * 24;
    const int h = rem / 3, qblk = rem - (rem / 3) * 3;
    const int w = threadIdx.x >> 6, ln = threadIdx.x & 63;
    const int l15 = ln & 15, l4 = ln >> 4;
    const int qr0 = qblk * 48 + w * 16;   // wave's first q-row

    const bf16* qbase = qbuf + ((size_t)(b * QN + qr0) * C_ + h * HD);
    const bf16* kh = kfr + (size_t)(b * NH + h) * 18 * 4096;
    const bf16* vh = vfr + (size_t)(b * NH + h) * 18 * 4096;

    // ---- per-wave relative-position bias tables (wave's own 16 rows) ----
    {
        int qr = ln >> 2, kkg = ln & 3;
        int row = qr0 + qr;
        int y = row / 12, x = row - (row / 12) * 12;
        const short8* qrow = (const short8*)(qbuf + ((size_t)(b * QN + row) * C_ + h * HD));
        float sh[6] = {0, 0, 0, 0, 0, 0}, sw[6] = {0, 0, 0, 0, 0, 0};
        for (int c0 = 0; c0 < 16; c0++) {
            short8 qv = qrow[c0];
            float qf[8];
            #pragma unroll
            for (int j = 0; j < 8; j++) qf[j] = s2f(qv[j]);
            #pragma unroll
            for (int j = 0; j < 6; j++) {
                int kk = j * 4 + kkg;
                const f32x4* rh = (const f32x4*)(rph + (size_t)(2 * y - kk + 23) * HD + c0 * 8);
                const f32x4* rw = (const f32x4*)(rpw + (size_t)(2 * x - kk + 23) * HD + c0 * 8);
                f32x4 h0 = rh[0], h1 = rh[1], w0 = rw[0], w1 = rw[1];
                #pragma unroll
                for (int u = 0; u < 4; u++) {
                    sh[j] = fmaf(qf[u], h0[u], sh[j]);
                    sw[j] = fmaf(qf[u], w0[u], sw[j]);
                    sh[j] = fmaf(qf[u + 4], h1[u], sh[j]);
                    sw[j] = fmaf(qf[u + 4], w1[u], sw[j]);
                }
            }
        }
        #pragma unroll
        for (int j = 0; j < 6; j++) {
            relh[w][qr * 24 + j * 4 + kkg] = sh[j];
            relw[w][qr * 24 + j * 4 + kkg] = sw[j];
        }
    }
    asm volatile("s_waitcnt lgkmcnt(0)" ::: "memory");   // per-wave LDS visibility

    // ---- persistent q fragments (B-operand: row=q=l15, k=ks*32+l4*8+e) ----
    short8 qfr[4];
    #pragma unroll
    for (int ks = 0; ks < 4; ks++)
        qfr[ks] = *(const short8*)(qbase + (size_t)l15 * C_ + ks * 32 + l4 * 8);

    f32x4 zero = {0.f, 0.f, 0.f, 0.f};
    f32x4 Of[8];
    #pragma unroll
    for (int hf = 0; hf < 8; hf++) Of[hf] = zero;
    float mrun = -1e30f, lrun = 0.f;

    const float scale = 0.08838834764831845f;  // 1/sqrt(128)
    const int rbase = l15 * 24;                // this lane's q row in the wave table
    const int xsw = (l15 >> 1) & 3;            // P-bounce bank swizzle

    for (int kt = 0; kt < 18; kt++) {
        // ---- QK^T: K fragments in two 4-batches (each dead after its MFMAs) ----
        f32x4 S[2];
        {
            short8 kb[4];
            #pragma unroll
            for (int i = 0; i < 4; i++)
                kb[i] = *(const short8*)(kh + ((size_t)kt * 8 + i) * 512 + ln * 8);
            short8 kb2[4];
            #pragma unroll
            for (int i = 0; i < 4; i++)
                kb2[i] = *(const short8*)(kh + ((size_t)kt * 8 + 4 + i) * 512 + ln * 8);
            f32x4 a0 = zero, a1 = zero;
            #pragma unroll
            for (int ks = 0; ks < 4; ks++) a0 = MFMA(kb[ks], qfr[ks], a0);
            #pragma unroll
            for (int ks = 0; ks < 4; ks++) a1 = MFMA(kb2[ks], qfr[ks], a1);
            S[0] = a0; S[1] = a1;
        }
        __builtin_amdgcn_sched_barrier(0);   // keep V loads BELOW the K section
        // ---- V fragments (reuse K's registers; latency hides under softmax) ----
        short8 vb[8];
        #pragma unroll
        for (int i = 0; i < 8; i++)
            vb[i] = *(const short8*)(vh + ((size_t)kt * 8 + i) * 512 + ln * 8);
        // ---- scale + rel-pos bias (per-lane keys) ----
        #pragma unroll
        for (int kf = 0; kf < 2; kf++) {
            #pragma unroll
            for (int r = 0; r < 4; r++) {
                int key = kt * 32 + kf * 16 + l4 * 4 + r;
                int kr = key / 24, kc = key - kr * 24;
                S[kf][r] = S[kf][r] * scale + relh[w][rbase + kr] + relw[w][rbase + kc];
            }
        }
        // ---- in-lane softmax (row = this lane's q; 8 keys/lane, x4 lanes) ----
        float pm = fmaxf(fmaxf(fmaxf(S[0][0], S[0][1]), fmaxf(S[0][2], S[0][3])),
                         fmaxf(fmaxf(S[1][0], S[1][1]), fmaxf(S[1][2], S[1][3])));
        pm = fmaxf(pm, __shfl_xor(pm, 16, 64));
        pm = fmaxf(pm, __shfl_xor(pm, 32, 64));
        if (!__all(pm <= mrun + 8.f)) {       // defer-max (T13)
            float mn = fmaxf(mrun, pm);
            float alpha = __expf(mrun - mn);
            #pragma unroll
            for (int hf = 0; hf < 8; hf++)
                #pragma unroll
                for (int r = 0; r < 4; r++) Of[hf][r] *= alpha;
            lrun *= alpha;
            mrun = mn;
        }
        float ps = 0.f;
        #pragma unroll
        for (int kf = 0; kf < 2; kf++)
            #pragma unroll
            for (int r = 0; r < 4; r++) {
                float p = __expf(S[kf][r] - mrun);
                S[kf][r] = p;
                ps += p;
            }
        ps += __shfl_xor(ps, 16, 64);
        ps += __shfl_xor(ps, 32, 64);
        lrun += ps;
        // ---- pack P -> per-wave LDS bounce (64B rows, 16B-slot XOR swizzle) ----
        #pragma unroll
        for (int kf = 0; kf < 2; kf++) {
            unsigned u0 = bfbits(S[kf][0]) | (bfbits(S[kf][1]) << 16);
            unsigned u1 = bfbits(S[kf][2]) | (bfbits(S[kf][3]) << 16);
            int s16 = (kf * 2 + (l4 >> 1)) ^ xsw;
            *(unsigned long long*)(&plds[w][l15 * 64 + s16 * 16 + (l4 & 1) * 8]) =
                ((unsigned long long)u1 << 32) | u0;
        }
        // P B-frag: row=q=l15, key=l4*8+e (swizzled slot)
        short8 pf = *(const short8*)(&plds[w][l15 * 64 + (l4 ^ xsw) * 16]);
        // ---- PV swapped: Of[hd][q] ----
        #pragma unroll
        for (int hf = 0; hf < 8; hf++)
            Of[hf] = MFMA(vb[hf], pf, Of[hf]);
    }

    // epilogue: O/l + q residual; lane stores row q=l15, hd = hf*16 + l4*4 + r
    bf16* obase = attno + ((size_t)(b * QN + qr0) * C_ + h * HD);
    float inv = 1.f / lrun;
    #pragma unroll
    for (int hf = 0; hf < 8; hf++) {
        s16x4 qres = *(const s16x4*)(qbase + (size_t)l15 * C_ + hf * 16 + l4 * 4);
        s16x4 o;
        #pragma unroll
        for (int r = 0; r < 4; r++) {
            float v = Of[hf][r] * inv + s2f(qres[r]);
            o[r] = (short)bfbits(v);
        }
        *(s16x4*)(obase + (size_t)l15 * C_ + hf * 16 + l4 * 4) = o;
    }
}

extern "C" void kernel_launch(void* const* d_in, const int* in_sizes, int n_in,
                              void* d_out, int out_size, void* d_ws, size_t ws_size,
                              hipStream_t stream)
{
    const float* x   = (const float*)d_in[0];
    const float* Wq  = (const float*)d_in[1];
    const float* Wk  = (const float*)d_in[2];
    const float* Wv  = (const float*)d_in[3];
    const float* Wp  = (const float*)d_in[4];
    const float* bp  = (const float*)d_in[5];
    const float* rph = (const float*)d_in[6];
    const float* rpw = (const float*)d_in[7];

    char* ws = (char*)d_ws;
    const size_t MB = 1024 * 1024;
    bf16* Wqt  = (bf16*)(ws + 0 * MB);
    bf16* Wkt  = (bf16*)(ws + 2 * MB);
    bf16* Wvt  = (bf16*)(ws + 4 * MB);
    bf16* Wpt  = (bf16*)(ws + 6 * MB);
    bf16* xt   = (bf16*)(ws + 8 * MB);          // 144 MB, reused as attno
    bf16* kfrb = (bf16*)(ws + 152 * MB);        // 144 MB (frag-ready K)
    bf16* vfrb = (bf16*)(ws + 296 * MB);        // 144 MB (frag-ready V)
    bf16* xp   = (bf16*)(ws + 440 * MB);        // 36 MB
    bf16* qbuf = (bf16*)(ws + 476 * MB);        // 36 MB -> end 512 MB
    bf16* attno = xt;

    transpose_w4<<<dim3(32, 32, 4), 256, 0, stream>>>(Wq, Wk, Wv, Wp, (bf16*)ws);
    transpose_cvt<<<dim3(18, 32, 128), 256, 0, stream>>>(
        x, xt, 1024, 576, (size_t)1024 * 576, (size_t)576 * 1024);
    pool_kernel<<<dim3(B_ * QN), 256, 0, stream>>>(xt, xp);
    gemm_nt<3><<<dim3(576, 8), 256, 0, stream>>>(xt, Wkt, kfrb, nullptr);
    gemm_nt<4><<<dim3(8, 576), 256, 0, stream>>>(Wvt, xt, vfrb, nullptr);
    gemm_nt<0><<<dim3(144, 8), 256, 0, stream>>>(xp, Wqt, qbuf, nullptr);
    attn_kernel<<<dim3(B_ * NH * 3), 192, 0, stream>>>(qbuf, kfrb, vfrb, rph, rpw, attno);
    gemm_nt<2><<<dim3(8, 144), 256, 0, stream>>>(Wpt, attno, d_out, bp);
}

// Round 8
// 1258.493 us; speedup vs baseline: 1.0198x; 1.0180x over previous
//
#include <hip/hip_runtime.h>
#include <hip/hip_bf16.h>

using bf16 = __hip_bfloat16;
typedef __attribute__((ext_vector_type(8))) short short8;
typedef __attribute__((ext_vector_type(4))) short s16x4;
typedef __attribute__((ext_vector_type(4))) float f32x4;

#define MFMA(a,b,c) __builtin_amdgcn_mfma_f32_16x16x32_bf16(a, b, c, 0, 0, 0)

#define B_      128
#define C_      1024
#define NH      8
#define HD      128
#define HW      24
#define NTOK    576
#define QH      12
#define QN      144

static __device__ __forceinline__ float bf2f(bf16 v) { return __bfloat162float(v); }
static __device__ __forceinline__ bf16  f2bf(float v) { return __float2bfloat16(v); }
static __device__ __forceinline__ float s2f(short s) {
    return __uint_as_float(((unsigned)(unsigned short)s) << 16);
}
static __device__ __forceinline__ unsigned bfbits(float v) {
    bf16 t = f2bf(v);
    return (unsigned)*(unsigned short*)&t;
}

__device__ __forceinline__ void gll16(const bf16* src, bf16* dst_lds) {
    __builtin_amdgcn_global_load_lds(
        (__attribute__((address_space(1))) const unsigned int*)src,
        (__attribute__((address_space(3))) unsigned int*)dst_lds,
        16, 0, 0);
}

// ---------------- transpose + fp32->bf16 convert: out[c][r] = in[r][c] ----------------
__global__ __launch_bounds__(256) void transpose_cvt(
    const float* __restrict__ in, bf16* __restrict__ out,
    int R, int Ccols, size_t ibs, size_t obs)
{
    __shared__ float tile[32][33];
    const float* ib = in + (size_t)blockIdx.z * ibs;
    bf16* ob = out + (size_t)blockIdx.z * obs;
    int c0 = blockIdx.x * 32, r0 = blockIdx.y * 32;
    int tx = threadIdx.x & 31, ty = threadIdx.x >> 5;
    #pragma unroll
    for (int i = 0; i < 32; i += 8)
        tile[ty + i][tx] = ib[(size_t)(r0 + ty + i) * Ccols + c0 + tx];
    __syncthreads();
    #pragma unroll
    for (int i = 0; i < 32; i += 8)
        ob[(size_t)(c0 + ty + i) * R + r0 + tx] = f2bf(tile[tx][ty + i]);
}

// ---------------- 4 weight transposes in one launch (z selects weight) ----------------
__global__ __launch_bounds__(256) void transpose_w4(
    const float* __restrict__ p0, const float* __restrict__ p1,
    const float* __restrict__ p2, const float* __restrict__ p3,
    bf16* __restrict__ out)
{
    __shared__ float tile[32][33];
    int z = blockIdx.z;
    const float* ib = (z == 0) ? p0 : (z == 1) ? p1 : (z == 2) ? p2 : p3;
    bf16* ob = out + (size_t)z * 1048576;
    int c0 = blockIdx.x * 32, r0 = blockIdx.y * 32;
    int tx = threadIdx.x & 31, ty = threadIdx.x >> 5;
    #pragma unroll
    for (int i = 0; i < 32; i += 8)
        tile[ty + i][tx] = ib[(size_t)(r0 + ty + i) * 1024 + c0 + tx];
    __syncthreads();
    #pragma unroll
    for (int i = 0; i < 32; i += 8)
        ob[(size_t)(c0 + ty + i) * 1024 + r0 + tx] = f2bf(tile[tx][ty + i]);
}

// ---------------- 3x3 s2 avg pool (count_include_pad), xt[B*N][C] -> xp[B*qN][C] ------
__global__ __launch_bounds__(256) void pool_kernel(const bf16* __restrict__ xt,
                                                   bf16* __restrict__ xp)
{
    int bqn = blockIdx.x;
    int b = bqn / QN, qn = bqn % QN;
    int y = qn / QH, x = qn % QH;
    int t = threadIdx.x;
    float s0 = 0, s1 = 0, s2 = 0, s3 = 0;
    for (int dy = 0; dy < 3; dy++) {
        int hy = 2 * y - 1 + dy;
        if (hy < 0 || hy >= HW) continue;
        for (int dx = 0; dx < 3; dx++) {
            int hx = 2 * x - 1 + dx;
            if (hx < 0 || hx >= HW) continue;
            const bf16* row = xt + (size_t)(b * NTOK + hy * HW + hx) * C_;
            s0 += bf2f(row[t]);
            s1 += bf2f(row[t + 256]);
            s2 += bf2f(row[t + 512]);
            s3 += bf2f(row[t + 768]);
        }
    }
    bf16* o = xp + (size_t)bqn * C_;
    const float n = 1.f / 9.f;
    o[t] = f2bf(s0 * n); o[t + 256] = f2bf(s1 * n);
    o[t + 512] = f2bf(s2 * n); o[t + 768] = f2bf(s3 * n);
}

// ---------------- NT GEMM: C[m][n] = sum_k A[m][k]*Bt[n][k], K=1024 -------------------
// EPI 0: bf16 row-major [M][1024]
// EPI 2: fp32 out + bias: row=channel, col=token -> out[b*147456 + ch*144 + qn]
// EPI 3: K frag-ready (32-key tiles): row=token(b*576+n), col=channel
// EPI 4: V frag-ready (32-key tiles): row=channel, col=token(b*576+n)
template<int EPI>
__global__ __launch_bounds__(256, 2) void gemm_nt(
    const bf16* __restrict__ A, const bf16* __restrict__ Bt,
    void* __restrict__ Cout, const float* __restrict__ bias)
{
    __shared__ bf16 lds[2][2][128 * 64];
    const int tid = threadIdx.x;
    const int wv = tid >> 6, ln = tid & 63;
    const int m0 = blockIdx.x * 128, n0 = blockIdx.y * 128;
    const int wr = wv >> 1, wc = wv & 1;
    const int l15 = ln & 15, l4 = ln >> 4;
    const int r8 = ln >> 3, sl = ln & 7;
    const int sg = sl ^ r8;

    const bf16* gA = A + (size_t)m0 * C_;
    const bf16* gB = Bt + (size_t)n0 * C_;

    f32x4 zero = {0.f, 0.f, 0.f, 0.f};
    f32x4 acc[4][4];
    #pragma unroll
    for (int i = 0; i < 4; i++)
        #pragma unroll
        for (int j = 0; j < 4; j++) acc[i][j] = zero;

    auto stage = [&](int kt, int d) {
        const bf16* sa = gA + kt * 64;
        const bf16* sb = gB + kt * 64;
        bf16* la = lds[d][0];
        bf16* lb = lds[d][1];
        #pragma unroll
        for (int i = 0; i < 4; i++) {
            int chunk = wv * 4 + i;
            gll16(sa + (size_t)(chunk * 8 + r8) * C_ + sg * 8, la + chunk * 512);
            gll16(sb + (size_t)(chunk * 8 + r8) * C_ + sg * 8, lb + chunk * 512);
        }
    };

    stage(0, 0);
    asm volatile("s_waitcnt vmcnt(0)");
    __syncthreads();

    int cur = 0;
    for (int kt = 0; kt < 16; kt++) {
        if (kt < 15) stage(kt + 1, cur ^ 1);
        const bf16* la = lds[cur][0];
        const bf16* lb = lds[cur][1];
        #pragma unroll
        for (int ks = 0; ks < 2; ks++) {
            short8 af[4], bfr[4];
            #pragma unroll
            for (int fm = 0; fm < 4; fm++) {
                int row = wr * 64 + fm * 16 + l15;
                int slot = (ks * 4 + l4) ^ (row & 7);
                af[fm] = *(const short8*)((const char*)la + row * 128 + slot * 16);
            }
            #pragma unroll
            for (int fn = 0; fn < 4; fn++) {
                int row = wc * 64 + fn * 16 + l15;
                int slot = (ks * 4 + l4) ^ (row & 7);
                bfr[fn] = *(const short8*)((const char*)lb + row * 128 + slot * 16);
            }
            #pragma unroll
            for (int fm = 0; fm < 4; fm++)
                #pragma unroll
                for (int fn = 0; fn < 4; fn++)
                    acc[fm][fn] = MFMA(af[fm], bfr[fn], acc[fm][fn]);
        }
        asm volatile("s_waitcnt vmcnt(0)");
        __syncthreads();
        cur ^= 1;
    }

    #pragma unroll
    for (int fm = 0; fm < 4; fm++) {
        #pragma unroll
        for (int fn = 0; fn < 4; fn++) {
            #pragma unroll
            for (int r = 0; r < 4; r++) {
                int row = m0 + wr * 64 + fm * 16 + l4 * 4 + r;
                int col = n0 + wc * 64 + fn * 16 + l15;
                float v = acc[fm][fn][r];
                if constexpr (EPI == 0) {
                    ((bf16*)Cout)[(size_t)row * C_ + col] = f2bf(v);
                } else if constexpr (EPI == 2) {
                    int bb = col / QN, qn = col % QN;
                    ((float*)Cout)[(size_t)bb * (C_ * QN) + (size_t)row * QN + qn] =
                        v + bias[row];
                } else if constexpr (EPI == 3) {
                    // K frag-ready: row = global token, col = channel
                    int b = row / NTOK, n = row % NTOK;
                    int h = col >> 7, ci = col & 127;
                    int kt2 = n >> 5, kf = (n >> 4) & 1, klane = n & 15;
                    int ks2 = ci >> 5, chunk = (ci >> 3) & 3, e = ci & 7;
                    int lane = chunk * 16 + klane;
                    size_t addr = ((((size_t)(b * NH + h) * 18 + kt2) * 2 + kf) * 4 + ks2) * 512
                                  + lane * 8 + e;
                    ((bf16*)Cout)[addr] = f2bf(v);
                } else {
                    // V frag-ready: row = channel, col = global token
                    int b = col / NTOK, n = col % NTOK;
                    int h = row >> 7, ci = row & 127;
                    int hf = (ci >> 4) & 7, lanelo = ci & 15;
                    int kt2 = n >> 5, chunk = (n >> 3) & 3, e = n & 7;
                    int lane = chunk * 16 + lanelo;
                    size_t addr = (((size_t)(b * NH + h) * 18 + kt2) * 8 + hf) * 512
                                  + lane * 8 + e;
                    ((bf16*)Cout)[addr] = f2bf(v);
                }
            }
        }
    }
}

// ---------------- fused pooled-Q attention, barrier-free, spill-free -------------------
// grid: B*NH*3 blocks of 192 thr (3 waves); each wave owns 16 q-rows, independent.
// K fragments: direct global->VGPR (transient). V: async global->per-wave-LDS via
// global_load_lds (never occupies VGPRs), consumed frag-at-a-time by ds_read_b128 in PV.
// Issue order K-then-V puts K oldest in the vmcnt FIFO: QK starts at vmcnt(8) while the
// V stage is still in flight; one vmcnt(0) before PV. No __syncthreads anywhere.
__global__ __launch_bounds__(192) void attn_kernel(
    const bf16* __restrict__ qbuf, const bf16* __restrict__ kfr,
    const bf16* __restrict__ vfr, const float* __restrict__ rph,
    const float* __restrict__ rpw, bf16* __restrict__ attno)
{
    __shared__ float relh[3][16 * 24];    // 4.5 KB
    __shared__ float relw[3][16 * 24];    // 4.5 KB
    __shared__ char  plds[3][1024];       // 3 KB
    __shared__ bf16  vlds[3][4096];       // 24 KB  -> 36 KB total, 4 blocks/CU

    const int work = ((blockIdx.x & 7) * 384) + (blockIdx.x >> 3);   // m157 swizzle
    const int b = work / 24;
    const int rem = work - b * 24;
    const int h = rem / 3, qblk = rem - (rem / 3) * 3;
    const int w = threadIdx.x >> 6, ln = threadIdx.x & 63;
    const int l15 = ln & 15, l4 = ln >> 4;
    const int qr0 = qblk * 48 + w * 16;   // wave's first q-row

    const bf16* qbase = qbuf + ((size_t)(b * QN + qr0) * C_ + h * HD);
    const bf16* kh = kfr + (size_t)(b * NH + h) * 18 * 4096;
    const bf16* vh = vfr + (size_t)(b * NH + h) * 18 * 4096;
    bf16* vdst = &vlds[w][0];

    // ---- per-wave relative-position bias tables (wave's own 16 rows) ----
    {
        int qr = ln >> 2, kkg = ln & 3;
        int row = qr0 + qr;
        int y = row / 12, x = row - (row / 12) * 12;
        const short8* qrow = (const short8*)(qbuf + ((size_t)(b * QN + row) * C_ + h * HD));
        float sh[6] = {0, 0, 0, 0, 0, 0}, sw[6] = {0, 0, 0, 0, 0, 0};
        for (int c0 = 0; c0 < 16; c0++) {
            short8 qv = qrow[c0];
            float qf[8];
            #pragma unroll
            for (int j = 0; j < 8; j++) qf[j] = s2f(qv[j]);
            #pragma unroll
            for (int j = 0; j < 6; j++) {
                int kk = j * 4 + kkg;
                const f32x4* rh = (const f32x4*)(rph + (size_t)(2 * y - kk + 23) * HD + c0 * 8);
                const f32x4* rw = (const f32x4*)(rpw + (size_t)(2 * x - kk + 23) * HD + c0 * 8);
                f32x4 h0 = rh[0], h1 = rh[1], w0 = rw[0], w1 = rw[1];
                #pragma unroll
                for (int u = 0; u < 4; u++) {
                    sh[j] = fmaf(qf[u], h0[u], sh[j]);
                    sw[j] = fmaf(qf[u], w0[u], sw[j]);
                    sh[j] = fmaf(qf[u + 4], h1[u], sh[j]);
                    sw[j] = fmaf(qf[u + 4], w1[u], sw[j]);
                }
            }
        }
        #pragma unroll
        for (int j = 0; j < 6; j++) {
            relh[w][qr * 24 + j * 4 + kkg] = sh[j];
            relw[w][qr * 24 + j * 4 + kkg] = sw[j];
        }
    }
    asm volatile("s_waitcnt lgkmcnt(0)" ::: "memory");   // per-wave LDS visibility

    // ---- persistent q fragments (B-operand: row=q=l15, k=ks*32+l4*8+e) ----
    short8 qfr[4];
    #pragma unroll
    for (int ks = 0; ks < 4; ks++)
        qfr[ks] = *(const short8*)(qbase + (size_t)l15 * C_ + ks * 32 + l4 * 8);

    f32x4 zero = {0.f, 0.f, 0.f, 0.f};
    f32x4 Of[8];
    #pragma unroll
    for (int hf = 0; hf < 8; hf++) Of[hf] = zero;
    float mrun = -1e30f, lrun = 0.f;

    const float scale = 0.08838834764831845f;  // 1/sqrt(128)
    const int rbase = l15 * 24;                // this lane's q row in the wave table
    const int xsw = (l15 >> 1) & 3;            // P-bounce bank swizzle

    for (int kt = 0; kt < 18; kt++) {
        // ---- K fragment loads FIRST (oldest in vmcnt FIFO) ----
        short8 kb[4], kb2[4];
        #pragma unroll
        for (int i = 0; i < 4; i++)
            kb[i] = *(const short8*)(kh + ((size_t)kt * 8 + i) * 512 + ln * 8);
        #pragma unroll
        for (int i = 0; i < 4; i++)
            kb2[i] = *(const short8*)(kh + ((size_t)kt * 8 + 4 + i) * 512 + ln * 8);
        // ---- V -> per-wave LDS (async; lands during QK + softmax) ----
        __builtin_amdgcn_sched_barrier(0);   // don't hoist stage above prior PV reads
        #pragma unroll
        for (int s = 0; s < 8; s++)
            gll16(vh + (size_t)kt * 4096 + s * 512 + ln * 8, vdst + s * 512);
        // ---- QK^T (kb ready at vmcnt(8); V stage still flying) ----
        f32x4 S[2];
        {
            f32x4 a0 = zero, a1 = zero;
            #pragma unroll
            for (int ks = 0; ks < 4; ks++) a0 = MFMA(kb[ks], qfr[ks], a0);
            #pragma unroll
            for (int ks = 0; ks < 4; ks++) a1 = MFMA(kb2[ks], qfr[ks], a1);
            S[0] = a0; S[1] = a1;
        }
        // ---- scale + rel-pos bias (per-lane keys) ----
        #pragma unroll
        for (int kf = 0; kf < 2; kf++) {
            #pragma unroll
            for (int r = 0; r < 4; r++) {
                int key = kt * 32 + kf * 16 + l4 * 4 + r;
                int kr = key / 24, kc = key - kr * 24;
                S[kf][r] = S[kf][r] * scale + relh[w][rbase + kr] + relw[w][rbase + kc];
            }
        }
        // ---- in-lane softmax (row = this lane's q; 8 keys/lane, x4 lanes) ----
        float pm = fmaxf(fmaxf(fmaxf(S[0][0], S[0][1]), fmaxf(S[0][2], S[0][3])),
                         fmaxf(fmaxf(S[1][0], S[1][1]), fmaxf(S[1][2], S[1][3])));
        pm = fmaxf(pm, __shfl_xor(pm, 16, 64));
        pm = fmaxf(pm, __shfl_xor(pm, 32, 64));
        if (!__all(pm <= mrun + 8.f)) {       // defer-max (T13)
            float mn = fmaxf(mrun, pm);
            float alpha = __expf(mrun - mn);
            #pragma unroll
            for (int hf = 0; hf < 8; hf++)
                #pragma unroll
                for (int r = 0; r < 4; r++) Of[hf][r] *= alpha;
            lrun *= alpha;
            mrun = mn;
        }
        float ps = 0.f;
        #pragma unroll
        for (int kf = 0; kf < 2; kf++)
            #pragma unroll
            for (int r = 0; r < 4; r++) {
                float p = __expf(S[kf][r] - mrun);
                S[kf][r] = p;
                ps += p;
            }
        ps += __shfl_xor(ps, 16, 64);
        ps += __shfl_xor(ps, 32, 64);
        lrun += ps;
        // ---- pack P -> per-wave LDS bounce (64B rows, 16B-slot XOR swizzle) ----
        #pragma unroll
        for (int kf = 0; kf < 2; kf++) {
            unsigned u0 = bfbits(S[kf][0]) | (bfbits(S[kf][1]) << 16);
            unsigned u1 = bfbits(S[kf][2]) | (bfbits(S[kf][3]) << 16);
            int s16 = (kf * 2 + (l4 >> 1)) ^ xsw;
            *(unsigned long long*)(&plds[w][l15 * 64 + s16 * 16 + (l4 & 1) * 8]) =
                ((unsigned long long)u1 << 32) | u0;
        }
        short8 pf = *(const short8*)(&plds[w][l15 * 64 + (l4 ^ xsw) * 16]);
        // ---- wait V staged, then PV from LDS (frag-at-a-time, no bulk registers) ----
        asm volatile("s_waitcnt vmcnt(0)");
        __builtin_amdgcn_sched_barrier(0);
        #pragma unroll
        for (int hf = 0; hf < 8; hf++) {
            short8 vb = *(const short8*)(vdst + hf * 512 + ln * 8);
            Of[hf] = MFMA(vb, pf, Of[hf]);
        }
    }

    // epilogue: O/l + q residual; lane stores row q=l15, hd = hf*16 + l4*4 + r
    bf16* obase = attno + ((size_t)(b * QN + qr0) * C_ + h * HD);
    float inv = 1.f / lrun;
    #pragma unroll
    for (int hf = 0; hf < 8; hf++) {
        s16x4 qres = *(const s16x4*)(qbase + (size_t)l15 * C_ + hf * 16 + l4 * 4);
        s16x4 o;
        #pragma unroll
        for (int r = 0; r < 4; r++) {
            float v = Of[hf][r] * inv + s2f(qres[r]);
            o[r] = (short)bfbits(v);
        }
        *(s16x4*)(obase + (size_t)l15 * C_ + hf * 16 + l4 * 4) = o;
    }
}

extern "C" void kernel_launch(void* const* d_in, const int* in_sizes, int n_in,
                              void* d_out, int out_size, void* d_ws, size_t ws_size,
                              hipStream_t stream)
{
    const float* x   = (const float*)d_in[0];
    const float* Wq  = (const float*)d_in[1];
    const float* Wk  = (const float*)d_in[2];
    const float* Wv  = (const float*)d_in[3];
    const float* Wp  = (const float*)d_in[4];
    const float* bp  = (const float*)d_in[5];
    const float* rph = (const float*)d_in[6];
    const float* rpw = (const float*)d_in[7];

    char* ws = (char*)d_ws;
    const size_t MB = 1024 * 1024;
    bf16* Wqt  = (bf16*)(ws + 0 * MB);
    bf16* Wkt  = (bf16*)(ws + 2 * MB);
    bf16* Wvt  = (bf16*)(ws + 4 * MB);
    bf16* Wpt  = (bf16*)(ws + 6 * MB);
    bf16* xt   = (bf16*)(ws + 8 * MB);          // 144 MB, reused as attno
    bf16* kfrb = (bf16*)(ws + 152 * MB);        // 144 MB (frag-ready K)
    bf16* vfrb = (bf16*)(ws + 296 * MB);        // 144 MB (frag-ready V)
    bf16* xp   = (bf16*)(ws + 440 * MB);        // 36 MB
    bf16* qbuf = (bf16*)(ws + 476 * MB);        // 36 MB -> end 512 MB
    bf16* attno = xt;

    transpose_w4<<<dim3(32, 32, 4), 256, 0, stream>>>(Wq, Wk, Wv, Wp, (bf16*)ws);
    transpose_cvt<<<dim3(18, 32, 128), 256, 0, stream>>>(
        x, xt, 1024, 576, (size_t)1024 * 576, (size_t)576 * 1024);
    pool_kernel<<<dim3(B_ * QN), 256, 0, stream>>>(xt, xp);
    gemm_nt<3><<<dim3(576, 8), 256, 0, stream>>>(xt, Wkt, kfrb, nullptr);
    gemm_nt<4><<<dim3(8, 576), 256, 0, stream>>>(Wvt, xt, vfrb, nullptr);
    gemm_nt<0><<<dim3(144, 8), 256, 0, stream>>>(xp, Wqt, qbuf, nullptr);
    attn_kernel<<<dim3(B_ * NH * 3), 192, 0, stream>>>(qbuf, kfrb, vfrb, rph, rpw, attno);
    gemm_nt<2><<<dim3(8, 144), 256, 0, stream>>>(Wpt, attno, d_out, bp);
}